// Round 13
// baseline (22.664 us; speedup 1.0000x reference)
//
#include <hip/hip_runtime.h>

#define BB 4
#define SS 8192
#define DD 1024
#define TPB 1024
#define GROUP 64          // output rows per block (4 per wave)

typedef float vf4 __attribute__((ext_vector_type(4)));

// R12 structure (best measured: 16.9 us) + non-temporal x loads:
//  - wave-local dtype detect (1 KB window, no barrier)
//  - parallel cross-wave scan combine (one barrier)
//  - LDS scatter of the block's 64 source rows (one barrier)
//  - copy: nt loads (x rows are read-once), nt stores (write-once stream) —
//    L2 stays dedicated to the shared boundaries window.
__global__ __launch_bounds__(TPB) void chunk_block(const void* __restrict__ bptr,
                                                   const float* __restrict__ x,
                                                   float* __restrict__ out,
                                                   float* __restrict__ ntok,
                                                   int max_chunks, int ngroups) {
    const int b = blockIdx.x / ngroups;
    const int g = blockIdx.x % ngroups;
    const int row0 = g * GROUP;
    const int t = threadIdx.x;
    const int lane = t & 63;
    const int wave = t >> 6;

    // ---- wave-local dtype detect: 0=int32, 1=byte-bool, 2=float32 ----
    int f;
    {
        const uint4* __restrict__ wp = (const uint4*)bptr;
        uint4 w = wp[lane];                       // bytes [0, 1024)
        unsigned int o = w.x | w.y | w.z | w.w;
        const bool non = __any((o & 0xFEFEFEFEu) != 0u);  // any byte > 1 -> float32
        const bool mis = __any((o & 0xFFFFFF00u) != 0u);  // misaligned nonzero -> bool
        f = non ? 2 : (mis ? 1 : 0);
    }

    // ---- boundaries: 8 elements per thread -> bitmask ----
    unsigned int mask = 0;
    if (f == 0) {
        const int4* __restrict__ p = (const int4*)((const int*)bptr + b * SS);
        int4 w0 = p[t * 2], w1 = p[t * 2 + 1];
        int vi[8] = {w0.x, w0.y, w0.z, w0.w, w1.x, w1.y, w1.z, w1.w};
        #pragma unroll
        for (int k = 0; k < 8; ++k) mask |= (unsigned int)(vi[k] != 0) << k;
    } else if (f == 1) {
        const uint2* __restrict__ p = (const uint2*)((const unsigned char*)bptr + b * SS);
        uint2 w = p[t];
        unsigned int ws[2] = {w.x, w.y};
        #pragma unroll
        for (int k = 0; k < 8; ++k)
            mask |= (unsigned int)(((ws[k >> 2] >> ((k & 3) * 8)) & 0xFFu) != 0u) << k;
    } else {
        const float4* __restrict__ p = (const float4*)((const float*)bptr + b * SS);
        float4 w0 = p[t * 2], w1 = p[t * 2 + 1];
        float vf[8] = {w0.x, w0.y, w0.z, w0.w, w1.x, w1.y, w1.z, w1.w};
        #pragma unroll
        for (int k = 0; k < 8; ++k) mask |= (unsigned int)(vf[k] != 0.0f) << k;
    }
    const int cnt = __popc(mask);

    // ---- wave inclusive scan ----
    int scan = cnt;
    #pragma unroll
    for (int o = 1; o < 64; o <<= 1) {
        int n = __shfl_up(scan, o, 64);
        if (lane >= o) scan += n;
    }

    // ---- parallel cross-wave combine (one barrier, no serial stage) ----
    __shared__ int waveTot[16];
    __shared__ int s_rowj[GROUP];
    if (lane == 63) waveTot[wave] = scan;
    __syncthreads();
    int waveOff = 0, T = 0;
    #pragma unroll
    for (int w = 0; w < 16; ++w) {
        const int wt = waveTot[w];
        waveOff += (w < wave) ? wt : 0;
        T += wt;
    }

    // ---- dests; capture the GROUP source rows this block owns ----
    int tr = waveOff + (scan - cnt);   // exclusive prefix of trues
    #pragma unroll
    for (int k = 0; k < 8; ++k) {
        const int j = t * 8 + k;
        int dest;
        if ((mask >> k) & 1u) { dest = tr; tr++; }
        else                  { dest = T + (j - tr); }
        const int rel = dest - row0;
        if ((unsigned)rel < (unsigned)GROUP) s_rowj[rel] = j;
    }
    if (g == 0 && t == 0) ntok[b] = (float)T;
    __syncthreads();

    // ---- copy: each of 16 waves moves 4 rows; nt loads, nt stores ----
    const int rbase = wave * 4;
    const vf4* src[4];
    vf4* dst[4];
    bool valid[4];
    #pragma unroll
    for (int r = 0; r < 4; ++r) {
        const int c = row0 + rbase + r;
        valid[r] = c < max_chunks;
        const int cc = valid[r] ? c : 0;
        const int j = s_rowj[valid[r] ? (rbase + r) : 0];
        src[r] = (const vf4*)(x + ((long long)b * SS + j) * DD);
        dst[r] = (vf4*)(out + ((long long)b * max_chunks + cc) * (long long)DD);
    }
    vf4 v[4][4];
    #pragma unroll
    for (int r = 0; r < 4; ++r)
        #pragma unroll
        for (int q = 0; q < 4; ++q)
            v[r][q] = __builtin_nontemporal_load(&src[r][lane + 64 * q]);
    #pragma unroll
    for (int r = 0; r < 4; ++r)
        if (valid[r])
            #pragma unroll
            for (int q = 0; q < 4; ++q)
                __builtin_nontemporal_store(v[r][q], &dst[r][lane + 64 * q]);
}

extern "C" void kernel_launch(void* const* d_in, const int* in_sizes, int n_in,
                              void* d_out, int out_size, void* d_ws, size_t ws_size,
                              hipStream_t stream) {
    const float* x = (const float*)d_in[0];
    const void* bptr = d_in[1];
    float* out = (float*)d_out;

    const int max_chunks = (out_size - BB) / (BB * DD);
    const int ngroups = (max_chunks + GROUP - 1) / GROUP;
    float* ntok = out + (long long)BB * max_chunks * DD;

    chunk_block<<<BB * ngroups, TPB, 0, stream>>>(bptr, x, out, ntok, max_chunks, ngroups);
}

// Round 14
// 16.659 us; speedup vs baseline: 1.3605x; 1.3605x over previous
//
#include <hip/hip_runtime.h>

#define BB 4
#define SS 8192
#define DD 1024
#define TPB 1024
#define GROUP 64          // output rows per block (4 per wave)

typedef float vf4 __attribute__((ext_vector_type(4)));

// Best measured configuration (R12, 16.9 us):
//  - single dispatch, 132 fat blocks (1024 thr), 64 output rows per block
//  - wave-local dtype detect (1 KB window, no barrier)
//  - parallel cross-wave scan combine (one barrier)
//  - LDS scatter of the block's 64 source rows (one barrier)
//  - copy: CACHED loads (x rows are ~50% L3-resident across replays),
//    NON-TEMPORAL stores (write-once stream; keeps L2 for shared metadata).
__global__ __launch_bounds__(TPB) void chunk_block(const void* __restrict__ bptr,
                                                   const float* __restrict__ x,
                                                   float* __restrict__ out,
                                                   float* __restrict__ ntok,
                                                   int max_chunks, int ngroups) {
    const int b = blockIdx.x / ngroups;
    const int g = blockIdx.x % ngroups;
    const int row0 = g * GROUP;
    const int t = threadIdx.x;
    const int lane = t & 63;
    const int wave = t >> 6;

    // ---- wave-local dtype detect: 0=int32, 1=byte-bool, 2=float32 ----
    int f;
    {
        const uint4* __restrict__ wp = (const uint4*)bptr;
        uint4 w = wp[lane];                       // bytes [0, 1024)
        unsigned int o = w.x | w.y | w.z | w.w;
        const bool non = __any((o & 0xFEFEFEFEu) != 0u);  // any byte > 1 -> float32
        const bool mis = __any((o & 0xFFFFFF00u) != 0u);  // misaligned nonzero -> bool
        f = non ? 2 : (mis ? 1 : 0);
    }

    // ---- boundaries: 8 elements per thread -> bitmask ----
    unsigned int mask = 0;
    if (f == 0) {
        const int4* __restrict__ p = (const int4*)((const int*)bptr + b * SS);
        int4 w0 = p[t * 2], w1 = p[t * 2 + 1];
        int vi[8] = {w0.x, w0.y, w0.z, w0.w, w1.x, w1.y, w1.z, w1.w};
        #pragma unroll
        for (int k = 0; k < 8; ++k) mask |= (unsigned int)(vi[k] != 0) << k;
    } else if (f == 1) {
        const uint2* __restrict__ p = (const uint2*)((const unsigned char*)bptr + b * SS);
        uint2 w = p[t];
        unsigned int ws[2] = {w.x, w.y};
        #pragma unroll
        for (int k = 0; k < 8; ++k)
            mask |= (unsigned int)(((ws[k >> 2] >> ((k & 3) * 8)) & 0xFFu) != 0u) << k;
    } else {
        const float4* __restrict__ p = (const float4*)((const float*)bptr + b * SS);
        float4 w0 = p[t * 2], w1 = p[t * 2 + 1];
        float vf[8] = {w0.x, w0.y, w0.z, w0.w, w1.x, w1.y, w1.z, w1.w};
        #pragma unroll
        for (int k = 0; k < 8; ++k) mask |= (unsigned int)(vf[k] != 0.0f) << k;
    }
    const int cnt = __popc(mask);

    // ---- wave inclusive scan ----
    int scan = cnt;
    #pragma unroll
    for (int o = 1; o < 64; o <<= 1) {
        int n = __shfl_up(scan, o, 64);
        if (lane >= o) scan += n;
    }

    // ---- parallel cross-wave combine (one barrier, no serial stage) ----
    __shared__ int waveTot[16];
    __shared__ int s_rowj[GROUP];
    if (lane == 63) waveTot[wave] = scan;
    __syncthreads();
    int waveOff = 0, T = 0;
    #pragma unroll
    for (int w = 0; w < 16; ++w) {
        const int wt = waveTot[w];
        waveOff += (w < wave) ? wt : 0;
        T += wt;
    }

    // ---- dests; capture the GROUP source rows this block owns ----
    int tr = waveOff + (scan - cnt);   // exclusive prefix of trues
    #pragma unroll
    for (int k = 0; k < 8; ++k) {
        const int j = t * 8 + k;
        int dest;
        if ((mask >> k) & 1u) { dest = tr; tr++; }
        else                  { dest = T + (j - tr); }
        const int rel = dest - row0;
        if ((unsigned)rel < (unsigned)GROUP) s_rowj[rel] = j;
    }
    if (g == 0 && t == 0) ntok[b] = (float)T;
    __syncthreads();

    // ---- copy: each of 16 waves moves 4 rows; cached loads, nt stores ----
    const int rbase = wave * 4;
    const vf4* src[4];
    vf4* dst[4];
    bool valid[4];
    #pragma unroll
    for (int r = 0; r < 4; ++r) {
        const int c = row0 + rbase + r;
        valid[r] = c < max_chunks;
        const int cc = valid[r] ? c : 0;
        const int j = s_rowj[valid[r] ? (rbase + r) : 0];
        src[r] = (const vf4*)(x + ((long long)b * SS + j) * DD);
        dst[r] = (vf4*)(out + ((long long)b * max_chunks + cc) * (long long)DD);
    }
    vf4 v[4][4];
    #pragma unroll
    for (int r = 0; r < 4; ++r)
        #pragma unroll
        for (int q = 0; q < 4; ++q)
            v[r][q] = src[r][lane + 64 * q];
    #pragma unroll
    for (int r = 0; r < 4; ++r)
        if (valid[r])
            #pragma unroll
            for (int q = 0; q < 4; ++q)
                __builtin_nontemporal_store(v[r][q], &dst[r][lane + 64 * q]);
}

extern "C" void kernel_launch(void* const* d_in, const int* in_sizes, int n_in,
                              void* d_out, int out_size, void* d_ws, size_t ws_size,
                              hipStream_t stream) {
    const float* x = (const float*)d_in[0];
    const void* bptr = d_in[1];
    float* out = (float*)d_out;

    const int max_chunks = (out_size - BB) / (BB * DD);
    const int ngroups = (max_chunks + GROUP - 1) / GROUP;
    float* ntok = out + (long long)BB * max_chunks * DD;

    chunk_block<<<BB * ngroups, TPB, 0, stream>>>(bptr, x, out, ntok, max_chunks, ngroups);
}